// Round 2
// baseline (331.099 us; speedup 1.0000x reference)
//
#include <hip/hip_runtime.h>

typedef float  f32x4  __attribute__((ext_vector_type(4)));
typedef float  f4v    __attribute__((ext_vector_type(4)));
typedef __bf16 bf16x8 __attribute__((ext_vector_type(8)));
typedef __bf16 bf16x4 __attribute__((ext_vector_type(4)));
typedef unsigned short ushort_t;

#define AS1 __attribute__((address_space(1)))
#define AS3 __attribute__((address_space(3)))

static __device__ __forceinline__ void gload_lds16(const void* g, void* l) {
  __builtin_amdgcn_global_load_lds((const AS1 void*)g, (AS3 void*)l, 16, 0, 0);
}

// mish(x) = x * tanh(softplus(x)) = x * u/(u+2), u = t*(t+2), t = e^x.
// 1 transcendental + few VALU. Guard x>15 (tanh saturated); x<<0 -> 0 naturally.
static __device__ __forceinline__ float mishf(float x) {
  float t = __expf(x);
  float u = t * (t + 2.f);
  float y = x * __fdividef(u, u + 2.f);
  return (x > 15.f) ? x : y;
}

// ---------------- weight cast fp32 -> bf16 (packed layout) ----------------
__global__ __launch_bounds__(256) void castw(
    const float* __restrict__ Wq, const float* __restrict__ Wk,
    const float* __restrict__ Wv, const float* __restrict__ Wp,
    const float* __restrict__ W1, const float* __restrict__ W2,
    __bf16* __restrict__ out)
{
  const int i = (blockIdx.x * 256 + threadIdx.x) * 4;
  const float* src; int off = i;
  if      (i < 65536)  { src = Wq; }
  else if (i < 131072) { src = Wk; off = i - 65536; }
  else if (i < 196608) { src = Wv; off = i - 131072; }
  else if (i < 262144) { src = Wp; off = i - 196608; }
  else if (i < 524288) { src = W1; off = i - 262144; }
  else                 { src = W2; off = i - 524288; }
  const f4v v = *(const f4v*)(src + off);
  bf16x4 o;
  #pragma unroll
  for (int j = 0; j < 4; ++j) o[j] = (__bf16)v[j];
  *(bf16x4*)(out + i) = o;
}

// ---------------- LayerNorm row kernel: fp32 in -> bf16 out ----------------
__global__ __launch_bounds__(256) void ln_rows(
    const float* __restrict__ X, const float* __restrict__ g,
    const float* __restrict__ b, __bf16* __restrict__ Y)
{
  const int l = threadIdx.x & 63;
  const size_t row = (size_t)blockIdx.x * 4 + (threadIdx.x >> 6);
  const f4v x = *(const f4v*)(X + row * 256 + l * 4);
  float s = x[0] + x[1] + x[2] + x[3];
  float q = x[0]*x[0] + x[1]*x[1] + x[2]*x[2] + x[3]*x[3];
  #pragma unroll
  for (int d = 1; d < 64; d <<= 1) { s += __shfl_xor(s, d); q += __shfl_xor(q, d); }
  const float mu = s * (1.f / 256.f);
  const float rs = rsqrtf(q * (1.f / 256.f) - mu * mu + 1e-5f);
  const f4v gv = *(const f4v*)(g + l * 4);
  const f4v bv = *(const f4v*)(b + l * 4);
  bf16x4 o;
  #pragma unroll
  for (int j = 0; j < 4; ++j) o[j] = (__bf16)((x[j] - mu) * rs * gv[j] + bv[j]);
  *(bf16x4*)(Y + row * 256 + l * 4) = o;
}

// ---------------- GEMM  C[M=32768, N] = act(A @ Bw^T + bias) (+res) -------
// 128x128 tile, BK=32, 4 waves (2x2 of 64x64). Epilogue staged through LDS
// (union with staging buffers) for coalesced 16B stores; residual read is
// coalesced in the read-back phase.
template<int ACT, int RES, int OUTBF>
__global__ __launch_bounds__(256, 2) void gemm_bt(
    const __bf16* __restrict__ A, const __bf16* __restrict__ Bw,
    const float* __restrict__ bias, const float* __restrict__ res,
    void* __restrict__ Cv, int N, int K)
{
  __shared__ union U {
    struct { __bf16 A[2][128][32]; __bf16 B[2][128][32]; } st; // 32 KB
    __bf16 cb[128 * 144];                                      // 36.9 KB
    float  cf[64 * 144];                                       // 36.9 KB
  } lds;
  const int tid = threadIdx.x;
  const int l = tid & 63;
  const int w = tid >> 6, wr = w >> 1, wc = w & 1;
  const int mt = blockIdx.x, nt = blockIdx.y;

  const __bf16* ga = A  + (size_t)(mt * 128 + (tid >> 2)) * K + (tid & 3) * 8;
  const __bf16* gb = Bw + (size_t)(nt * 128 + (tid >> 2)) * K + (tid & 3) * 8;

  auto stage = [&](int buf, int kt) {
    const __bf16* a = ga + kt * 32;
    const __bf16* b = gb + kt * 32;
    gload_lds16(a,          &lds.st.A[buf][tid >> 2][(tid & 3) * 8]);
    gload_lds16(a + 64 * K, &lds.st.A[buf][64 + (tid >> 2)][(tid & 3) * 8]);
    gload_lds16(b,          &lds.st.B[buf][tid >> 2][(tid & 3) * 8]);
    gload_lds16(b + 64 * K, &lds.st.B[buf][64 + (tid >> 2)][(tid & 3) * 8]);
  };

  f32x4 acc[4][4] = {};
  const int NK = K >> 5;
  stage(0, 0);
  __syncthreads();
  int cur = 0;
  for (int kt = 0;;) {
    if (kt + 1 < NK) stage(cur ^ 1, kt + 1);
    bf16x8 af[4], bfr[4];
    #pragma unroll
    for (int m = 0; m < 4; ++m)
      af[m] = *(const bf16x8*)&lds.st.A[cur][wr * 64 + m * 16 + (l & 15)][(l >> 4) * 8];
    #pragma unroll
    for (int n = 0; n < 4; ++n)
      bfr[n] = *(const bf16x8*)&lds.st.B[cur][wc * 64 + n * 16 + (l & 15)][(l >> 4) * 8];
    #pragma unroll
    for (int m = 0; m < 4; ++m)
      #pragma unroll
      for (int n = 0; n < 4; ++n)
        acc[m][n] = __builtin_amdgcn_mfma_f32_16x16x32_bf16(af[m], bfr[n], acc[m][n], 0, 0, 0);
    if (++kt == NK) break;
    __syncthreads();
    cur ^= 1;
  }

  __syncthreads();   // staging buffers retire; LDS is repurposed below

  if (OUTBF) {
    // stage full 128x128 bf16 tile, row stride 144 (288B = conflict-free)
    #pragma unroll
    for (int n = 0; n < 4; ++n) {
      const int col = wc * 64 + n * 16 + (l & 15);
      const float bb = bias[nt * 128 + col];
      #pragma unroll
      for (int m = 0; m < 4; ++m) {
        const int lr0 = wr * 64 + m * 16 + ((l >> 4) << 2);
        #pragma unroll
        for (int r = 0; r < 4; ++r) {
          float v = acc[m][n][r] + bb;
          if (ACT) v = mishf(v);
          lds.cb[(lr0 + r) * 144 + col] = (__bf16)v;
        }
      }
    }
    __syncthreads();
    #pragma unroll
    for (int j = 0; j < 8; ++j) {
      const int rr = j * 16 + (tid >> 4);
      bf16x8 v = *(const bf16x8*)&lds.cb[rr * 144 + (tid & 15) * 8];
      *(bf16x8*)((__bf16*)Cv + (size_t)(mt * 128 + rr) * N + nt * 128 + (tid & 15) * 8) = v;
    }
  } else {
    // fp32 out in two 64-row passes; residual added in coalesced read-back
    #pragma unroll
    for (int p = 0; p < 2; ++p) {
      if (p) __syncthreads();
      #pragma unroll
      for (int n = 0; n < 4; ++n) {
        const int col = wc * 64 + n * 16 + (l & 15);
        const float bb = bias[nt * 128 + col];
        #pragma unroll
        for (int mm = 0; mm < 2; ++mm) {
          const int m = p * 2 + mm;
          const int lr0 = wr * 32 + mm * 16 + ((l >> 4) << 2);
          #pragma unroll
          for (int r = 0; r < 4; ++r) {
            float v = acc[m][n][r] + bb;
            if (ACT) v = mishf(v);
            lds.cf[(lr0 + r) * 144 + col] = v;
          }
        }
      }
      __syncthreads();
      #pragma unroll
      for (int j = 0; j < 8; ++j) {
        const int lr = j * 8 + (tid >> 5);
        const int gr = mt * 128 + lr + (lr & 32) + 32 * p;   // local->global row
        const int gc = nt * 128 + (tid & 31) * 4;
        f4v v = *(const f4v*)&lds.cf[lr * 144 + (tid & 31) * 4];
        if (RES) v += *(const f4v*)&res[(size_t)gr * N + gc];
        *(f4v*)((float*)Cv + (size_t)gr * N + gc) = v;
      }
    }
  }
}

// ---------------- flash attention (seq-chunk heads, softmax then /16) ------
__global__ __launch_bounds__(512) void attn_fwd(
    const __bf16* __restrict__ Qm, const __bf16* __restrict__ Km,
    const __bf16* __restrict__ Vm, __bf16* __restrict__ Om)
{
  __shared__ __bf16 Ks[2][32][256];   // K tile, XOR-swizzled rows
  __shared__ __bf16 Vs[2][256][32];   // V^T tile [n][k]
  __shared__ __bf16 Ps[8][16][32];    // per-wave P relayout buffer
  const int tid = threadIdx.x, l = tid & 63, w = tid >> 6;
  const size_t base = (size_t)blockIdx.y << 18;          // bh * 1024 * 256
  const int qr0 = blockIdx.x * 128 + w * 16;

  bf16x8 qf[8];
  {
    const __bf16* qp = Qm + base + (size_t)(qr0 + (l & 15)) * 256 + ((l >> 4) << 3);
    #pragma unroll
    for (int s = 0; s < 8; ++s) qf[s] = *(const bf16x8*)(qp + s * 32);
  }
  f32x4 acc[16] = {};
  float lacc[4] = {0.f, 0.f, 0.f, 0.f};

  const int kec = tid & 31, kr_ = tid >> 5;
  const int vp = tid & 15, vc = tid >> 4;
  const __bf16* gK = Km + base + kec * 8;
  const __bf16* gV = Vm + base + vc * 8;

  uint4 rk0, rk1, rv0, rv1;
  auto ldKV = [&](int kt) {
    const __bf16* k0 = gK + (size_t)(kt * 32 + kr_) * 256;
    rk0 = *(const uint4*)k0;
    rk1 = *(const uint4*)(k0 + 16 * 256);
    const __bf16* v0 = gV + (size_t)(kt * 32 + vp * 2) * 256;
    rv0 = *(const uint4*)v0;
    rv1 = *(const uint4*)(v0 + 256);
  };
  auto wrKV = [&](int buf) {
    char* kb = (char*)&Ks[buf][0][0];
    const int a0 = (kr_ * 512 + kec * 16) ^ ((kr_ & 15) << 4);
    const int a1 = ((kr_ + 16) * 512 + kec * 16) ^ (((kr_ + 16) & 15) << 4);
    *(uint4*)(kb + a0) = rk0;
    *(uint4*)(kb + a1) = rk1;
    const ushort_t* s0 = (const ushort_t*)&rv0;
    const ushort_t* s1 = (const ushort_t*)&rv1;
    #pragma unroll
    for (int i = 0; i < 8; ++i) {
      unsigned pk = (unsigned)s0[i] | ((unsigned)s1[i] << 16);
      *(unsigned*)&Vs[buf][vc * 8 + i][vp * 2] = pk;
    }
  };

  ldKV(0); wrKV(0);
  __syncthreads();
  int cur = 0;
  for (int kt = 0;;) {
    if (kt + 1 < 32) ldKV(kt + 1);
    f32x4 S[2] = {};
    const char* kbase = (const char*)&Ks[cur][0][0];
    #pragma unroll
    for (int t = 0; t < 2; ++t) {
      const int kcol = t * 16 + (l & 15);
      const int swz = (kcol & 15) << 4;
      #pragma unroll
      for (int s = 0; s < 8; ++s) {
        uint4 kf = *(const uint4*)(kbase + ((kcol * 512 + s * 64 + ((l >> 4) << 4)) ^ swz));
        S[t] = __builtin_amdgcn_mfma_f32_16x16x32_bf16(qf[s], __builtin_bit_cast(bf16x8, kf), S[t], 0, 0, 0);
      }
    }
    #pragma unroll
    for (int t = 0; t < 2; ++t)
      #pragma unroll
      for (int r = 0; r < 4; ++r) {
        float p = __expf(S[t][r]);
        lacc[r] += p;
        Ps[w][((l >> 4) << 2) + r][t * 16 + (l & 15)] = (__bf16)p;
      }
    bf16x8 pf = *(const bf16x8*)&Ps[w][l & 15][(l >> 4) << 3];
    #pragma unroll
    for (int n = 0; n < 16; ++n) {
      uint4 vf = *(const uint4*)&Vs[cur][n * 16 + (l & 15)][(l >> 4) << 3];
      acc[n] = __builtin_amdgcn_mfma_f32_16x16x32_bf16(pf, __builtin_bit_cast(bf16x8, vf), acc[n], 0, 0, 0);
    }
    if (++kt == 32) break;
    wrKV(cur ^ 1);
    __syncthreads();
    cur ^= 1;
  }
  f32x4 inv;
  #pragma unroll
  for (int r = 0; r < 4; ++r) {
    float s = lacc[r];
    s += __shfl_xor(s, 1); s += __shfl_xor(s, 2);
    s += __shfl_xor(s, 4); s += __shfl_xor(s, 8);
    inv[r] = 1.f / (16.f * s);
  }
  __bf16* op = Om + base + (size_t)(qr0 + ((l >> 4) << 2)) * 256 + (l & 15);
  #pragma unroll
  for (int n = 0; n < 16; ++n)
    #pragma unroll
    for (int r = 0; r < 4; ++r)
      op[(size_t)r * 256 + n * 16] = (__bf16)(acc[n][r] * inv[r]);
}

// ---------------- host launch ----------------
extern "C" void kernel_launch(void* const* d_in, const int* in_sizes, int n_in,
                              void* d_out, int out_size, void* d_ws, size_t ws_size,
                              hipStream_t stream)
{
  const float* x    = (const float*)d_in[0];
  const float* ln1w = (const float*)d_in[1];
  const float* ln1b = (const float*)d_in[2];
  const float* Wq   = (const float*)d_in[3];
  const float* bq   = (const float*)d_in[4];
  const float* Wk   = (const float*)d_in[5];
  const float* bk   = (const float*)d_in[6];
  const float* Wv   = (const float*)d_in[7];
  const float* bv   = (const float*)d_in[8];
  const float* Wp   = (const float*)d_in[9];
  const float* bp   = (const float*)d_in[10];
  const float* ln2w = (const float*)d_in[11];
  const float* ln2b = (const float*)d_in[12];
  const float* W1   = (const float*)d_in[13];
  const float* b1   = (const float*)d_in[14];
  const float* W2   = (const float*)d_in[15];
  const float* b2   = (const float*)d_in[16];

  char* ws = (char*)d_ws;
  __bf16* wb = (__bf16*)(ws);                  // 786432 bf16 weights
  __bf16* y  = (__bf16*)(ws + 1572864);        // LN1 out (reused as attn out)
  __bf16* qb = (__bf16*)(ws + 18350080);       // q (reused as LN2 out)
  __bf16* kb = (__bf16*)(ws + 35127296);
  __bf16* vb = (__bf16*)(ws + 51904512);
  float*  x1 = (float*)(ws + 68681728);        // fp32 residual stream
  __bf16* h1 = (__bf16*)(ws + 102236160);      // MLP hidden (32768x1024)
  __bf16* ao = y;
  __bf16* hb = qb;
  float*  outp = (float*)d_out;

  castw<<<768, 256, 0, stream>>>(Wq, Wk, Wv, Wp, W1, W2, wb);
  ln_rows<<<8192, 256, 0, stream>>>(x, ln1w, ln1b, y);
  gemm_bt<0,0,1><<<dim3(256, 2), 256, 0, stream>>>(y,  wb,          bq, nullptr, qb,   256, 256);
  gemm_bt<0,0,1><<<dim3(256, 2), 256, 0, stream>>>(y,  wb + 65536,  bk, nullptr, kb,   256, 256);
  gemm_bt<0,0,1><<<dim3(256, 2), 256, 0, stream>>>(y,  wb + 131072, bv, nullptr, vb,   256, 256);
  attn_fwd<<<dim3(8, 32), 512, 0, stream>>>(qb, kb, vb, ao);
  gemm_bt<0,1,0><<<dim3(256, 2), 256, 0, stream>>>(ao, wb + 196608, bp, x,       x1,   256, 256);
  ln_rows<<<8192, 256, 0, stream>>>(x1, ln2w, ln2b, hb);
  gemm_bt<1,0,1><<<dim3(256, 8), 256, 0, stream>>>(hb, wb + 262144, b1, nullptr, h1,  1024, 256);
  gemm_bt<1,1,0><<<dim3(256, 2), 256, 0, stream>>>(h1, wb + 524288, b2, x1,      outp, 256, 1024);
}

// Round 3
// 330.103 us; speedup vs baseline: 1.0030x; 1.0030x over previous
//
#include <hip/hip_runtime.h>

typedef float  f32x4  __attribute__((ext_vector_type(4)));
typedef float  f4v    __attribute__((ext_vector_type(4)));
typedef __bf16 bf16x8 __attribute__((ext_vector_type(8)));
typedef __bf16 bf16x4 __attribute__((ext_vector_type(4)));
typedef unsigned short ushort_t;

#define AS1 __attribute__((address_space(1)))
#define AS3 __attribute__((address_space(3)))

static __device__ __forceinline__ void gload_lds16(const void* g, void* l) {
  __builtin_amdgcn_global_load_lds((const AS1 void*)g, (AS3 void*)l, 16, 0, 0);
}

// mish(x) = x * tanh(softplus(x)) = x * u/(u+2), u = t*(t+2), t = e^x.
static __device__ __forceinline__ float mishf(float x) {
  float t = __expf(x);
  float u = t * (t + 2.f);
  float y = x * __fdividef(u, u + 2.f);
  return (x > 15.f) ? x : y;
}

// ---------------- weight cast fp32 -> bf16 (packed layout) ----------------
__global__ __launch_bounds__(256) void castw(
    const float* __restrict__ Wq, const float* __restrict__ Wk,
    const float* __restrict__ Wv, const float* __restrict__ Wp,
    const float* __restrict__ W1, const float* __restrict__ W2,
    __bf16* __restrict__ out)
{
  const int i = (blockIdx.x * 256 + threadIdx.x) * 4;
  const float* src; int off = i;
  if      (i < 65536)  { src = Wq; }
  else if (i < 131072) { src = Wk; off = i - 65536; }
  else if (i < 196608) { src = Wv; off = i - 131072; }
  else if (i < 262144) { src = Wp; off = i - 196608; }
  else if (i < 524288) { src = W1; off = i - 262144; }
  else                 { src = W2; off = i - 524288; }
  const f4v v = *(const f4v*)(src + off);
  bf16x4 o;
  #pragma unroll
  for (int j = 0; j < 4; ++j) o[j] = (__bf16)v[j];
  *(bf16x4*)(out + i) = o;
}

// ---------------- LayerNorm row kernel: fp32 in -> bf16 out ----------------
__global__ __launch_bounds__(256) void ln_rows(
    const float* __restrict__ X, const float* __restrict__ g,
    const float* __restrict__ b, __bf16* __restrict__ Y)
{
  const int l = threadIdx.x & 63;
  const size_t row = (size_t)blockIdx.x * 4 + (threadIdx.x >> 6);
  const f4v x = *(const f4v*)(X + row * 256 + l * 4);
  float s = x[0] + x[1] + x[2] + x[3];
  float q = x[0]*x[0] + x[1]*x[1] + x[2]*x[2] + x[3]*x[3];
  #pragma unroll
  for (int d = 1; d < 64; d <<= 1) { s += __shfl_xor(s, d); q += __shfl_xor(q, d); }
  const float mu = s * (1.f / 256.f);
  const float rs = rsqrtf(q * (1.f / 256.f) - mu * mu + 1e-5f);
  const f4v gv = *(const f4v*)(g + l * 4);
  const f4v bv = *(const f4v*)(b + l * 4);
  bf16x4 o;
  #pragma unroll
  for (int j = 0; j < 4; ++j) o[j] = (__bf16)((x[j] - mu) * rs * gv[j] + bv[j]);
  *(bf16x4*)(Y + row * 256 + l * 4) = o;
}

// ---------------- GEMM  C[M=32768, N] = act(A @ Bw^T + bias) (+res) -------
// 128x128 tile, BK=32, 4 waves (2x2 of 64x64). Epilogue staged through LDS:
// bf16 stride 136 elems (272B): write groups 2-way (free), b128 reads clean;
// fp32 stride 132 floats (528B): writes and f4 reads conflict-free.
template<int ACT, int RES, int OUTBF>
__global__ __launch_bounds__(256, 2) void gemm_bt(
    const __bf16* __restrict__ A, const __bf16* __restrict__ Bw,
    const float* __restrict__ bias, const float* __restrict__ res,
    void* __restrict__ Cv, int N, int K)
{
  __shared__ union U {
    struct { __bf16 A[2][128][32]; __bf16 B[2][128][32]; } st; // 32 KB
    __bf16 cb[128 * 136];                                      // 34 KB
    float  cf[64 * 132];                                       // 33 KB
  } lds;
  const int tid = threadIdx.x;
  const int l = tid & 63;
  const int w = tid >> 6, wr = w >> 1, wc = w & 1;
  const int mt = blockIdx.x, nt = blockIdx.y;

  const __bf16* ga = A  + (size_t)(mt * 128 + (tid >> 2)) * K + (tid & 3) * 8;
  const __bf16* gb = Bw + (size_t)(nt * 128 + (tid >> 2)) * K + (tid & 3) * 8;

  auto stage = [&](int buf, int kt) {
    const __bf16* a = ga + kt * 32;
    const __bf16* b = gb + kt * 32;
    gload_lds16(a,          &lds.st.A[buf][tid >> 2][(tid & 3) * 8]);
    gload_lds16(a + 64 * K, &lds.st.A[buf][64 + (tid >> 2)][(tid & 3) * 8]);
    gload_lds16(b,          &lds.st.B[buf][tid >> 2][(tid & 3) * 8]);
    gload_lds16(b + 64 * K, &lds.st.B[buf][64 + (tid >> 2)][(tid & 3) * 8]);
  };

  f32x4 acc[4][4] = {};
  const int NK = K >> 5;
  stage(0, 0);
  __syncthreads();
  int cur = 0;
  for (int kt = 0;;) {
    if (kt + 1 < NK) stage(cur ^ 1, kt + 1);
    bf16x8 af[4], bfr[4];
    #pragma unroll
    for (int m = 0; m < 4; ++m)
      af[m] = *(const bf16x8*)&lds.st.A[cur][wr * 64 + m * 16 + (l & 15)][(l >> 4) * 8];
    #pragma unroll
    for (int n = 0; n < 4; ++n)
      bfr[n] = *(const bf16x8*)&lds.st.B[cur][wc * 64 + n * 16 + (l & 15)][(l >> 4) * 8];
    #pragma unroll
    for (int m = 0; m < 4; ++m)
      #pragma unroll
      for (int n = 0; n < 4; ++n)
        acc[m][n] = __builtin_amdgcn_mfma_f32_16x16x32_bf16(af[m], bfr[n], acc[m][n], 0, 0, 0);
    if (++kt == NK) break;
    __syncthreads();
    cur ^= 1;
  }

  __syncthreads();   // staging buffers retire; LDS is repurposed below

  if (OUTBF) {
    // stage full 128x128 bf16 tile, row stride 136 elems (272 B)
    #pragma unroll
    for (int n = 0; n < 4; ++n) {
      const int col = wc * 64 + n * 16 + (l & 15);
      const float bb = bias[nt * 128 + col];
      #pragma unroll
      for (int m = 0; m < 4; ++m) {
        const int lr0 = wr * 64 + m * 16 + ((l >> 4) << 2);
        #pragma unroll
        for (int r = 0; r < 4; ++r) {
          float v = acc[m][n][r] + bb;
          if (ACT) v = mishf(v);
          lds.cb[(lr0 + r) * 136 + col] = (__bf16)v;
        }
      }
    }
    __syncthreads();
    #pragma unroll
    for (int j = 0; j < 8; ++j) {
      const int rr = j * 16 + (tid >> 4);
      bf16x8 v = *(const bf16x8*)&lds.cb[rr * 136 + (tid & 15) * 8];
      *(bf16x8*)((__bf16*)Cv + (size_t)(mt * 128 + rr) * N + nt * 128 + (tid & 15) * 8) = v;
    }
  } else {
    // fp32 out in two 64-row passes, stride 132 floats (528 B)
    #pragma unroll
    for (int p = 0; p < 2; ++p) {
      if (p) __syncthreads();
      #pragma unroll
      for (int n = 0; n < 4; ++n) {
        const int col = wc * 64 + n * 16 + (l & 15);
        const float bb = bias[nt * 128 + col];
        #pragma unroll
        for (int mm = 0; mm < 2; ++mm) {
          const int m = p * 2 + mm;
          const int lr0 = wr * 32 + mm * 16 + ((l >> 4) << 2);
          #pragma unroll
          for (int r = 0; r < 4; ++r) {
            float v = acc[m][n][r] + bb;
            if (ACT) v = mishf(v);
            lds.cf[(lr0 + r) * 132 + col] = v;
          }
        }
      }
      __syncthreads();
      #pragma unroll
      for (int j = 0; j < 8; ++j) {
        const int lr = j * 8 + (tid >> 5);
        const int gr = mt * 128 + lr + (lr & 32) + 32 * p;   // local->global row
        const int gc = nt * 128 + (tid & 31) * 4;
        f4v v = *(const f4v*)&lds.cf[lr * 132 + (tid & 31) * 4];
        if (RES) v += *(const f4v*)&res[(size_t)gr * N + gc];
        *(f4v*)((float*)Cv + (size_t)gr * N + gc) = v;
      }
    }
  }
}

// ---------------- flash attention (seq-chunk heads, softmax then /16) ------
__global__ __launch_bounds__(512) void attn_fwd(
    const __bf16* __restrict__ Qm, const __bf16* __restrict__ Km,
    const __bf16* __restrict__ Vm, __bf16* __restrict__ Om)
{
  __shared__ __bf16 Ks[2][32][256];   // K tile, XOR-swizzled rows
  __shared__ __bf16 Vs[2][256][32];   // V^T tile [n][k]
  __shared__ __bf16 Ps[8][16][32];    // per-wave P relayout buffer
  const int tid = threadIdx.x, l = tid & 63, w = tid >> 6;
  const size_t base = (size_t)blockIdx.y << 18;          // bh * 1024 * 256
  const int qr0 = blockIdx.x * 128 + w * 16;

  bf16x8 qf[8];
  {
    const __bf16* qp = Qm + base + (size_t)(qr0 + (l & 15)) * 256 + ((l >> 4) << 3);
    #pragma unroll
    for (int s = 0; s < 8; ++s) qf[s] = *(const bf16x8*)(qp + s * 32);
  }
  f32x4 acc[16] = {};
  float lacc[4] = {0.f, 0.f, 0.f, 0.f};

  const int kec = tid & 31, kr_ = tid >> 5;
  const int vp = tid & 15, vc = tid >> 4;
  const __bf16* gK = Km + base + kec * 8;
  const __bf16* gV = Vm + base + vc * 8;

  uint4 rk0, rk1, rv0, rv1;
  auto ldKV = [&](int kt) {
    const __bf16* k0 = gK + (size_t)(kt * 32 + kr_) * 256;
    rk0 = *(const uint4*)k0;
    rk1 = *(const uint4*)(k0 + 16 * 256);
    const __bf16* v0 = gV + (size_t)(kt * 32 + vp * 2) * 256;
    rv0 = *(const uint4*)v0;
    rv1 = *(const uint4*)(v0 + 256);
  };
  auto wrKV = [&](int buf) {
    char* kb = (char*)&Ks[buf][0][0];
    const int a0 = (kr_ * 512 + kec * 16) ^ ((kr_ & 15) << 4);
    const int a1 = ((kr_ + 16) * 512 + kec * 16) ^ (((kr_ + 16) & 15) << 4);
    *(uint4*)(kb + a0) = rk0;
    *(uint4*)(kb + a1) = rk1;
    const ushort_t* s0 = (const ushort_t*)&rv0;
    const ushort_t* s1 = (const ushort_t*)&rv1;
    #pragma unroll
    for (int i = 0; i < 8; ++i) {
      unsigned pk = (unsigned)s0[i] | ((unsigned)s1[i] << 16);
      *(unsigned*)&Vs[buf][vc * 8 + i][vp * 2] = pk;
    }
  };

  ldKV(0); wrKV(0);
  __syncthreads();
  int cur = 0;
  for (int kt = 0;;) {
    if (kt + 1 < 32) ldKV(kt + 1);
    f32x4 S[2] = {};
    const char* kbase = (const char*)&Ks[cur][0][0];
    #pragma unroll
    for (int t = 0; t < 2; ++t) {
      const int kcol = t * 16 + (l & 15);
      const int swz = (kcol & 15) << 4;
      #pragma unroll
      for (int s = 0; s < 8; ++s) {
        uint4 kf = *(const uint4*)(kbase + ((kcol * 512 + s * 64 + ((l >> 4) << 4)) ^ swz));
        S[t] = __builtin_amdgcn_mfma_f32_16x16x32_bf16(qf[s], __builtin_bit_cast(bf16x8, kf), S[t], 0, 0, 0);
      }
    }
    #pragma unroll
    for (int t = 0; t < 2; ++t)
      #pragma unroll
      for (int r = 0; r < 4; ++r) {
        float p = __expf(S[t][r]);
        lacc[r] += p;
        Ps[w][((l >> 4) << 2) + r][t * 16 + (l & 15)] = (__bf16)p;
      }
    bf16x8 pf = *(const bf16x8*)&Ps[w][l & 15][(l >> 4) << 3];
    #pragma unroll
    for (int n = 0; n < 16; ++n) {
      uint4 vf = *(const uint4*)&Vs[cur][n * 16 + (l & 15)][(l >> 4) << 3];
      acc[n] = __builtin_amdgcn_mfma_f32_16x16x32_bf16(pf, __builtin_bit_cast(bf16x8, vf), acc[n], 0, 0, 0);
    }
    if (++kt == 32) break;
    wrKV(cur ^ 1);
    __syncthreads();
    cur ^= 1;
  }
  f32x4 inv;
  #pragma unroll
  for (int r = 0; r < 4; ++r) {
    float s = lacc[r];
    s += __shfl_xor(s, 1); s += __shfl_xor(s, 2);
    s += __shfl_xor(s, 4); s += __shfl_xor(s, 8);
    inv[r] = 1.f / (16.f * s);
  }
  __bf16* op = Om + base + (size_t)(qr0 + ((l >> 4) << 2)) * 256 + (l & 15);
  #pragma unroll
  for (int n = 0; n < 16; ++n)
    #pragma unroll
    for (int r = 0; r < 4; ++r)
      op[(size_t)r * 256 + n * 16] = (__bf16)(acc[n][r] * inv[r]);
}

// ---------------- host launch ----------------
extern "C" void kernel_launch(void* const* d_in, const int* in_sizes, int n_in,
                              void* d_out, int out_size, void* d_ws, size_t ws_size,
                              hipStream_t stream)
{
  const float* x    = (const float*)d_in[0];
  const float* ln1w = (const float*)d_in[1];
  const float* ln1b = (const float*)d_in[2];
  const float* Wq   = (const float*)d_in[3];
  const float* bq   = (const float*)d_in[4];
  const float* Wk   = (const float*)d_in[5];
  const float* bk   = (const float*)d_in[6];
  const float* Wv   = (const float*)d_in[7];
  const float* bv   = (const float*)d_in[8];
  const float* Wp   = (const float*)d_in[9];
  const float* bp   = (const float*)d_in[10];
  const float* ln2w = (const float*)d_in[11];
  const float* ln2b = (const float*)d_in[12];
  const float* W1   = (const float*)d_in[13];
  const float* b1   = (const float*)d_in[14];
  const float* W2   = (const float*)d_in[15];
  const float* b2   = (const float*)d_in[16];

  char* ws = (char*)d_ws;
  __bf16* wb = (__bf16*)(ws);                  // 786432 bf16 weights
  __bf16* y  = (__bf16*)(ws + 1572864);        // LN1 out (reused as attn out)
  __bf16* qb = (__bf16*)(ws + 18350080);       // q (reused as LN2 out)
  __bf16* kb = (__bf16*)(ws + 35127296);
  __bf16* vb = (__bf16*)(ws + 51904512);
  float*  x1 = (float*)(ws + 68681728);        // fp32 residual stream
  __bf16* h1 = (__bf16*)(ws + 102236160);      // MLP hidden (32768x1024)
  __bf16* ao = y;
  __bf16* hb = qb;
  float*  outp = (float*)d_out;

  castw<<<768, 256, 0, stream>>>(Wq, Wk, Wv, Wp, W1, W2, wb);
  ln_rows<<<8192, 256, 0, stream>>>(x, ln1w, ln1b, y);
  gemm_bt<0,0,1><<<dim3(256, 2), 256, 0, stream>>>(y,  wb,          bq, nullptr, qb,   256, 256);
  gemm_bt<0,0,1><<<dim3(256, 2), 256, 0, stream>>>(y,  wb + 65536,  bk, nullptr, kb,   256, 256);
  gemm_bt<0,0,1><<<dim3(256, 2), 256, 0, stream>>>(y,  wb + 131072, bv, nullptr, vb,   256, 256);
  attn_fwd<<<dim3(8, 32), 512, 0, stream>>>(qb, kb, vb, ao);
  gemm_bt<0,1,0><<<dim3(256, 2), 256, 0, stream>>>(ao, wb + 196608, bp, x,       x1,   256, 256);
  ln_rows<<<8192, 256, 0, stream>>>(x1, ln2w, ln2b, hb);
  gemm_bt<1,0,1><<<dim3(256, 8), 256, 0, stream>>>(hb, wb + 262144, b1, nullptr, h1,  1024, 256);
  gemm_bt<1,1,0><<<dim3(256, 2), 256, 0, stream>>>(h1, wb + 524288, b2, x1,      outp, 256, 1024);
}

// Round 4
// 260.006 us; speedup vs baseline: 1.2734x; 1.2696x over previous
//
#include <hip/hip_runtime.h>

typedef float  f32x4  __attribute__((ext_vector_type(4)));
typedef float  f4v    __attribute__((ext_vector_type(4)));
typedef __bf16 bf16x8 __attribute__((ext_vector_type(8)));
typedef __bf16 bf16x4 __attribute__((ext_vector_type(4)));
typedef unsigned short ushort_t;

#define AS1 __attribute__((address_space(1)))
#define AS3 __attribute__((address_space(3)))

static __device__ __forceinline__ void gload_lds16(const void* g, void* l) {
  __builtin_amdgcn_global_load_lds((const AS1 void*)g, (AS3 void*)l, 16, 0, 0);
}

// mish(x) = x * u/(u+2), u = t*(t+2), t = e^x; guard large x.
static __device__ __forceinline__ float mishf(float x) {
  float t = __expf(x);
  float u = t * (t + 2.f);
  float y = x * __fdividef(u, u + 2.f);
  return (x > 15.f) ? x : y;
}

// ---------------- weight cast fp32 -> bf16 (packed layout) ----------------
__global__ __launch_bounds__(256) void castw(
    const float* __restrict__ Wq, const float* __restrict__ Wk,
    const float* __restrict__ Wv, const float* __restrict__ Wp,
    const float* __restrict__ W1, const float* __restrict__ W2,
    __bf16* __restrict__ out)
{
  const int i = (blockIdx.x * 256 + threadIdx.x) * 4;
  const float* src; int off = i;
  if      (i < 65536)  { src = Wq; }
  else if (i < 131072) { src = Wk; off = i - 65536; }
  else if (i < 196608) { src = Wv; off = i - 131072; }
  else if (i < 262144) { src = Wp; off = i - 196608; }
  else if (i < 524288) { src = W1; off = i - 262144; }
  else                 { src = W2; off = i - 524288; }
  const f4v v = *(const f4v*)(src + off);
  bf16x4 o;
  #pragma unroll
  for (int j = 0; j < 4; ++j) o[j] = (__bf16)v[j];
  *(bf16x4*)(out + i) = o;
}

__global__ void packb(const float* __restrict__ a, const float* __restrict__ b,
                      const float* __restrict__ c, float* __restrict__ o) {
  int i = threadIdx.x;  // 768 threads
  o[i] = (i < 256) ? a[i] : (i < 512 ? b[i - 256] : c[i - 512]);
}

// ---------------- LayerNorm row kernel: fp32 in -> bf16 out ----------------
__global__ __launch_bounds__(256) void ln_rows(
    const float* __restrict__ X, const float* __restrict__ g,
    const float* __restrict__ b, __bf16* __restrict__ Y)
{
  const int l = threadIdx.x & 63;
  const size_t row = (size_t)blockIdx.x * 4 + (threadIdx.x >> 6);
  const f4v x = *(const f4v*)(X + row * 256 + l * 4);
  float s = x[0] + x[1] + x[2] + x[3];
  float q = x[0]*x[0] + x[1]*x[1] + x[2]*x[2] + x[3]*x[3];
  #pragma unroll
  for (int d = 1; d < 64; d <<= 1) { s += __shfl_xor(s, d); q += __shfl_xor(q, d); }
  const float mu = s * (1.f / 256.f);
  const float rs = rsqrtf(q * (1.f / 256.f) - mu * mu + 1e-5f);
  const f4v gv = *(const f4v*)(g + l * 4);
  const f4v bv = *(const f4v*)(b + l * 4);
  bf16x4 o;
  #pragma unroll
  for (int j = 0; j < 4; ++j) o[j] = (__bf16)((x[j] - mu) * rs * gv[j] + bv[j]);
  *(bf16x4*)(Y + row * 256 + l * 4) = o;
}

// ---------------- W-resident GEMM ----------------
// out[M][ldo] (+col0=nt*256) = act(A[M][K] @ W[nt*256..+256][K]^T + bias) (+res)
// K = KC*256. Block: 512 thr / 8 waves; wave owns 16 rows x 256 cols.
// W chunk [256][256] staged in LDS (128 KB) with 16B-unit XOR swizzle
// (pre-swizzled global source, linear gload_lds dest). A streamed from
// global straight into fragments. No barriers inside compute.
template<int KC, int ACT, int RES, int OUTBF>
__global__ __launch_bounds__(512, 2) void wgemm(
    const __bf16* __restrict__ A, const __bf16* __restrict__ Wg,
    const float* __restrict__ bias, const float* __restrict__ res,
    void* __restrict__ out, int ldo)
{
  constexpr int K = KC * 256;
  __shared__ __bf16 Wl[256 * 256];   // 128 KB
  const int tid = threadIdx.x, l = tid & 63, w = tid >> 6;
  const int mt = blockIdx.x, nt = blockIdx.y;
  const int row0 = mt * 128 + w * 16;
  const int col0 = nt * 256;
  const __bf16* Wbase = Wg + (size_t)nt * 256 * K;

  f32x4 acc[16] = {};

  for (int kc = 0; kc < KC; ++kc) {
    if (kc) __syncthreads();           // all waves done reading prev chunk
    // stage W chunk: LDS 16B-unit s = i*512 + tid; slot (r,u) <- W[r][u^(r&7)]
    #pragma unroll
    for (int i = 0; i < 16; ++i) {
      const int s = i * 512 + tid;
      const int r = s >> 5, u = s & 31;
      const __bf16* src = Wbase + (size_t)r * K + kc * 256 + ((u ^ (r & 7)) << 3);
      gload_lds16(src, (__bf16*)Wl + ((size_t)s << 3));
    }
    // A fragments (global, independent of LDS)
    bf16x8 af[8];
    const __bf16* ap = A + (size_t)(row0 + (l & 15)) * K + kc * 256 + ((l >> 4) << 3);
    #pragma unroll
    for (int s = 0; s < 8; ++s) af[s] = *(const bf16x8*)(ap + s * 32);
    __syncthreads();                   // W staged (vmcnt drained by barrier)
    #pragma unroll
    for (int n = 0; n < 16; ++n) {
      const int r = n * 16 + (l & 15);
      const int sw = r & 7;
      #pragma unroll
      for (int s = 0; s < 8; ++s) {
        const int u = s * 4 + (l >> 4);
        bf16x8 bfr = *(const bf16x8*)(Wl + (((r << 5) | (u ^ sw)) << 3));
        acc[n] = __builtin_amdgcn_mfma_f32_16x16x32_bf16(af[s], bfr, acc[n], 0, 0, 0);
      }
    }
  }
  __syncthreads();   // W retires; LDS reused for per-wave epilogue staging

  if (OUTBF) {
    // per-wave strip [16][260] bf16 (520B rows: groups at banks {0,8,16,24})
    __bf16* es = Wl + w * 4160;
    #pragma unroll
    for (int n = 0; n < 16; ++n) {
      const float bb = bias[col0 + n * 16 + (l & 15)];
      #pragma unroll
      for (int r = 0; r < 4; ++r) {
        float v = acc[n][r] + bb;
        if (ACT) v = mishf(v);
        es[(((l >> 4) << 2) + r) * 260 + n * 16 + (l & 15)] = (__bf16)v;
      }
    }
    const int rr = l >> 2;
    __bf16* op = (__bf16*)out + (size_t)(row0 + rr) * ldo + col0;
    const __bf16* er = es + rr * 260;
    #pragma unroll
    for (int i = 0; i < 8; ++i) {
      const int cu = (l & 3) + 4 * i;
      *(bf16x8*)(op + cu * 8) = *(const bf16x8*)(er + cu * 8);
    }
  } else {
    // two passes of 128 fp32 cols; strip [16][130] f32 (520B rows)
    float* es = (float*)Wl + w * 2080;
    #pragma unroll
    for (int p = 0; p < 2; ++p) {
      #pragma unroll
      for (int j = 0; j < 8; ++j) {
        const int n = p * 8 + j;
        const float bb = bias[col0 + n * 16 + (l & 15)];
        #pragma unroll
        for (int r = 0; r < 4; ++r) {
          float v = acc[n][r] + bb;
          if (ACT) v = mishf(v);
          es[(((l >> 4) << 2) + r) * 130 + j * 16 + (l & 15)] = v;
        }
      }
      const int rr = l >> 2;
      float* op = (float*)out + (size_t)(row0 + rr) * ldo + col0 + p * 128;
      const float* er = es + rr * 130;
      const float* rp = res + (size_t)(row0 + rr) * ldo + col0 + p * 128;
      #pragma unroll
      for (int i = 0; i < 8; ++i) {
        const int cu = (l & 3) + 4 * i;
        f4v v = *(const f4v*)(er + cu * 4);
        if (RES) v += *(const f4v*)(rp + cu * 4);
        *(f4v*)(op + cu * 4) = v;
      }
    }
  }
}

// ---------------- flash attention over packed QKV [M][768] ----------------
__global__ __launch_bounds__(512) void attn_fwd(
    const __bf16* __restrict__ QKV, __bf16* __restrict__ Om)
{
  __shared__ __bf16 Ks[2][32][256];   // K tile, XOR-swizzled rows
  __shared__ __bf16 Vs[2][256][32];   // V^T tile [n][k]
  __shared__ __bf16 Ps[8][16][32];    // per-wave P relayout buffer
  const int tid = threadIdx.x, l = tid & 63, w = tid >> 6;
  const size_t rbase = (size_t)blockIdx.y * 1024 * 768;   // bh row base (elems)
  const int qr0 = blockIdx.x * 128 + w * 16;

  bf16x8 qf[8];
  {
    const __bf16* qp = QKV + rbase + (size_t)(qr0 + (l & 15)) * 768 + ((l >> 4) << 3);
    #pragma unroll
    for (int s = 0; s < 8; ++s) qf[s] = *(const bf16x8*)(qp + s * 32);
  }
  f32x4 acc[16] = {};
  float lacc[4] = {0.f, 0.f, 0.f, 0.f};

  const int kec = tid & 31, kr_ = tid >> 5;
  const int vp = tid & 15, vc = tid >> 4;
  const __bf16* gK = QKV + 256 + rbase + kec * 8;
  const __bf16* gV = QKV + 512 + rbase + vc * 8;

  uint4 rk0, rk1, rv0, rv1;
  auto ldKV = [&](int kt) {
    const __bf16* k0 = gK + (size_t)(kt * 32 + kr_) * 768;
    rk0 = *(const uint4*)k0;
    rk1 = *(const uint4*)(k0 + 16 * 768);
    const __bf16* v0 = gV + (size_t)(kt * 32 + vp * 2) * 768;
    rv0 = *(const uint4*)v0;
    rv1 = *(const uint4*)(v0 + 768);
  };
  auto wrKV = [&](int buf) {
    char* kb = (char*)&Ks[buf][0][0];
    const int a0 = (kr_ * 512 + kec * 16) ^ ((kr_ & 15) << 4);
    const int a1 = ((kr_ + 16) * 512 + kec * 16) ^ (((kr_ + 16) & 15) << 4);
    *(uint4*)(kb + a0) = rk0;
    *(uint4*)(kb + a1) = rk1;
    const ushort_t* s0 = (const ushort_t*)&rv0;
    const ushort_t* s1 = (const ushort_t*)&rv1;
    #pragma unroll
    for (int i = 0; i < 8; ++i) {
      unsigned pk = (unsigned)s0[i] | ((unsigned)s1[i] << 16);
      *(unsigned*)&Vs[buf][vc * 8 + i][vp * 2] = pk;
    }
  };

  ldKV(0); wrKV(0);
  __syncthreads();
  int cur = 0;
  for (int kt = 0;;) {
    if (kt + 1 < 32) ldKV(kt + 1);
    f32x4 S[2] = {};
    const char* kbase = (const char*)&Ks[cur][0][0];
    #pragma unroll
    for (int t = 0; t < 2; ++t) {
      const int kcol = t * 16 + (l & 15);
      const int swz = (kcol & 15) << 4;
      #pragma unroll
      for (int s = 0; s < 8; ++s) {
        uint4 kf = *(const uint4*)(kbase + ((kcol * 512 + s * 64 + ((l >> 4) << 4)) ^ swz));
        S[t] = __builtin_amdgcn_mfma_f32_16x16x32_bf16(qf[s], __builtin_bit_cast(bf16x8, kf), S[t], 0, 0, 0);
      }
    }
    #pragma unroll
    for (int t = 0; t < 2; ++t)
      #pragma unroll
      for (int r = 0; r < 4; ++r) {
        float p = __expf(S[t][r]);
        lacc[r] += p;
        Ps[w][((l >> 4) << 2) + r][t * 16 + (l & 15)] = (__bf16)p;
      }
    bf16x8 pf = *(const bf16x8*)&Ps[w][l & 15][(l >> 4) << 3];
    #pragma unroll
    for (int n = 0; n < 16; ++n) {
      uint4 vf = *(const uint4*)&Vs[cur][n * 16 + (l & 15)][(l >> 4) << 3];
      acc[n] = __builtin_amdgcn_mfma_f32_16x16x32_bf16(pf, __builtin_bit_cast(bf16x8, vf), acc[n], 0, 0, 0);
    }
    if (++kt == 32) break;
    wrKV(cur ^ 1);
    __syncthreads();
    cur ^= 1;
  }
  f32x4 inv;
  #pragma unroll
  for (int r = 0; r < 4; ++r) {
    float s = lacc[r];
    s += __shfl_xor(s, 1); s += __shfl_xor(s, 2);
    s += __shfl_xor(s, 4); s += __shfl_xor(s, 8);
    inv[r] = 1.f / (16.f * s);
  }
  __bf16* op = Om + (size_t)(blockIdx.y * 1024 + qr0 + ((l >> 4) << 2)) * 256 + (l & 15);
  #pragma unroll
  for (int n = 0; n < 16; ++n)
    #pragma unroll
    for (int r = 0; r < 4; ++r)
      op[(size_t)r * 256 + n * 16] = (__bf16)(acc[n][r] * inv[r]);
}

// ---------------- host launch ----------------
extern "C" void kernel_launch(void* const* d_in, const int* in_sizes, int n_in,
                              void* d_out, int out_size, void* d_ws, size_t ws_size,
                              hipStream_t stream)
{
  const float* x    = (const float*)d_in[0];
  const float* ln1w = (const float*)d_in[1];
  const float* ln1b = (const float*)d_in[2];
  const float* Wq   = (const float*)d_in[3];
  const float* bq   = (const float*)d_in[4];
  const float* Wk   = (const float*)d_in[5];
  const float* bk   = (const float*)d_in[6];
  const float* Wv   = (const float*)d_in[7];
  const float* bv   = (const float*)d_in[8];
  const float* Wp   = (const float*)d_in[9];
  const float* bp   = (const float*)d_in[10];
  const float* ln2w = (const float*)d_in[11];
  const float* ln2b = (const float*)d_in[12];
  const float* W1   = (const float*)d_in[13];
  const float* b1   = (const float*)d_in[14];
  const float* W2   = (const float*)d_in[15];
  const float* b2   = (const float*)d_in[16];

  // ws layout (bytes), peak 136.3 MB:
  char* ws = (char*)d_ws;
  __bf16* wb   = (__bf16*)(ws);               // packed bf16 weights (1.5 MB)
  float*  bqkv = (float*)(ws + 1572864);      // packed qkv bias (3 KB)
  __bf16* y    = (__bf16*)(ws + 2097152);     // LN1 out / attn out (16 MB)
  __bf16* qkv  = (__bf16*)(ws + 18874368);    // packed QKV [M][768] (48 MB)
  float*  x1   = (float*)(ws + 18874368);     // residual fp32 (32 MB, aliases qkv lo)
  __bf16* hb   = (__bf16*)(ws + 52428800);    // LN2 out (16 MB, aliases qkv hi)
  __bf16* h1   = (__bf16*)(ws + 69206016);    // MLP hidden (64 MB)
  __bf16* ao   = y;
  float*  outp = (float*)d_out;

  castw<<<768, 256, 0, stream>>>(Wq, Wk, Wv, Wp, W1, W2, wb);
  packb<<<1, 768, 0, stream>>>(bq, bk, bv, bqkv);
  ln_rows<<<8192, 256, 0, stream>>>(x, ln1w, ln1b, y);
  wgemm<1,0,0,1><<<dim3(256, 3), 512, 0, stream>>>(y,  wb,          bqkv, nullptr, qkv, 768);
  attn_fwd<<<dim3(8, 32), 512, 0, stream>>>(qkv, ao);
  wgemm<1,0,1,0><<<dim3(256, 1), 512, 0, stream>>>(ao, wb + 196608, bp,   x,       x1,  256);
  ln_rows<<<8192, 256, 0, stream>>>(x1, ln2w, ln2b, hb);
  wgemm<1,1,0,1><<<dim3(256, 4), 512, 0, stream>>>(hb, wb + 262144, b1,   nullptr, h1,  1024);
  wgemm<4,1,1,0><<<dim3(256, 1), 512, 0, stream>>>(h1, wb + 524288, b2,   x1,      outp, 256);
}